// Round 2
// baseline (414.785 us; speedup 1.0000x reference)
//
#include <hip/hip_runtime.h>

// Trilinear interpolation of 2M points into a 128x128x128x16 fp32 grid.
// Layout: values[x][y][z][c], C=16 -> 64 B per voxel = 4 x float4.
// 4 lanes per point; lane handles channels [4*c4, 4*c4+4) via float4.
// Each thread processes TWO points (p and p + n/2) to double the number of
// outstanding 64B gather requests per wave (memory-latency bound kernel:
// VALUBusy 7.5%, HBM 43% of peak at round 1).

#define DD 128
#define HH 128
#define WW 128

__device__ __forceinline__ float4 lerp4(float4 a, float4 b, float t) {
    return make_float4(fmaf(b.x - a.x, t, a.x),
                       fmaf(b.y - a.y, t, a.y),
                       fmaf(b.z - a.z, t, a.z),
                       fmaf(b.w - a.w, t, a.w));
}

__global__ __launch_bounds__(256) void trilerp_kernel(
    const float* __restrict__ points,
    const float4* __restrict__ values,
    float4* __restrict__ out,
    int half_points)   // n_points / 2
{
    int t = blockIdx.x * blockDim.x + threadIdx.x;
    int p0 = t >> 2;       // first point index
    int c4 = t & 3;        // which float4 of the 16 channels
    if (p0 >= half_points) return;
    int p1 = p0 + half_points;

    // ---- load both points' coords ----
    float x0f = points[p0 * 3 + 0] * 20.0f;   // 1/VOXEL_SIZE = 20
    float y0f = points[p0 * 3 + 1] * 20.0f;
    float z0f = points[p0 * 3 + 2] * 20.0f;
    float x1f = points[p1 * 3 + 0] * 20.0f;
    float y1f = points[p1 * 3 + 1] * 20.0f;
    float z1f = points[p1 * 3 + 2] * 20.0f;

    // ---- point 0 indices ----
    int ax0 = min(max((int)floorf(x0f), 0), DD - 1);
    int ay0 = min(max((int)floorf(y0f), 0), HH - 1);
    int az0 = min(max((int)floorf(z0f), 0), WW - 1);
    int ax1 = min(ax0 + 1, DD - 1);
    int ay1 = min(ay0 + 1, HH - 1);
    int az1 = min(az0 + 1, WW - 1);
    float axd = x0f - (float)ax0;
    float ayd = y0f - (float)ay0;
    float azd = z0f - (float)az0;

    // ---- point 1 indices ----
    int bx0 = min(max((int)floorf(x1f), 0), DD - 1);
    int by0 = min(max((int)floorf(y1f), 0), HH - 1);
    int bz0 = min(max((int)floorf(z1f), 0), WW - 1);
    int bx1 = min(bx0 + 1, DD - 1);
    int by1 = min(by0 + 1, HH - 1);
    int bz1 = min(bz0 + 1, WW - 1);
    float bxd = x1f - (float)bx0;
    float byd = y1f - (float)by0;
    float bzd = z1f - (float)bz0;

    // float4 index: (((xi*128 + yi)*128 + zi) * 4) + c4
    #define VIDX(xi, yi, zi) ((((((xi) << 7) + (yi)) << 7) + (zi)) * 4 + c4)

    // ---- issue all 16 corner loads (independent -> all in flight) ----
    float4 a000 = values[VIDX(ax0, ay0, az0)];
    float4 a001 = values[VIDX(ax0, ay0, az1)];
    float4 a010 = values[VIDX(ax0, ay1, az0)];
    float4 a011 = values[VIDX(ax0, ay1, az1)];
    float4 a100 = values[VIDX(ax1, ay0, az0)];
    float4 a101 = values[VIDX(ax1, ay0, az1)];
    float4 a110 = values[VIDX(ax1, ay1, az0)];
    float4 a111 = values[VIDX(ax1, ay1, az1)];

    float4 b000 = values[VIDX(bx0, by0, bz0)];
    float4 b001 = values[VIDX(bx0, by0, bz1)];
    float4 b010 = values[VIDX(bx0, by1, bz0)];
    float4 b011 = values[VIDX(bx0, by1, bz1)];
    float4 b100 = values[VIDX(bx1, by0, bz0)];
    float4 b101 = values[VIDX(bx1, by0, bz1)];
    float4 b110 = values[VIDX(bx1, by1, bz0)];
    float4 b111 = values[VIDX(bx1, by1, bz1)];
    #undef VIDX

    // ---- reduce point 0 ----
    float4 a00 = lerp4(a000, a100, axd);
    float4 a01 = lerp4(a001, a101, axd);
    float4 a10 = lerp4(a010, a110, axd);
    float4 a11 = lerp4(a011, a111, axd);
    float4 a0 = lerp4(a00, a10, ayd);
    float4 a1 = lerp4(a01, a11, ayd);
    out[p0 * 4 + c4] = lerp4(a0, a1, azd);

    // ---- reduce point 1 ----
    float4 b00 = lerp4(b000, b100, bxd);
    float4 b01 = lerp4(b001, b101, bxd);
    float4 b10 = lerp4(b010, b110, bxd);
    float4 b11 = lerp4(b011, b111, bxd);
    float4 b0 = lerp4(b00, b10, byd);
    float4 b1 = lerp4(b01, b11, byd);
    out[p1 * 4 + c4] = lerp4(b0, b1, bzd);
}

extern "C" void kernel_launch(void* const* d_in, const int* in_sizes, int n_in,
                              void* d_out, int out_size, void* d_ws, size_t ws_size,
                              hipStream_t stream) {
    const float* points = (const float*)d_in[0];
    const float4* values = (const float4*)d_in[1];
    float4* out = (float4*)d_out;

    int n_points = in_sizes[0] / 3;
    int half = n_points / 2;               // N_POINTS = 2,000,000 (even)
    int total_threads = half * 4;
    int blocks = (total_threads + 255) / 256;

    trilerp_kernel<<<blocks, 256, 0, stream>>>(points, values, out, half);
}